// Round 10
// baseline (216.895 us; speedup 1.0000x reference)
//
#include <hip/hip_runtime.h>

#define N_NODESC 20000
#define N_EDGESC 1280000
#define NB 256          // csr-build blocks
#define EPB 5000        // edges per build block
#define CASTB 641       // cast blocks (1024 thr) inside fused cast+hist kernel

typedef short bf16x8 __attribute__((ext_vector_type(8)));
typedef float f32x4 __attribute__((ext_vector_type(4)));
typedef float f32x2 __attribute__((ext_vector_type(2)));

// ---- workspace layout (bytes, 16B-aligned) ----
constexpr size_t OFF_DEG      = 0;          // int[20000]
constexpr size_t OFF_ROWSTART = 81920;      // int[20001]
constexpr size_t OFF_INVDEG   = 163840;     // float[20000]
constexpr size_t OFF_BSUM     = 245760;     // int[128]
constexpr size_t OFF_S1       = 246784;     // float[20000]
constexpr size_t OFF_T1       = 326784;     // float[20000]
constexpr size_t OFF_PART     = 406784;     // float[5120] block partials
constexpr size_t OFF_HIST     = 427264;     // ushort[256][20000] = 10.24 MB
constexpr size_t OFF_CSR      = 10667264;   // ushort[1280000] (+128B overread pad)
constexpr size_t OFF_XB       = 13227392;   // bf16[20000][256] row-major = 10.24 MB
constexpr size_t OFF_MEANB    = 23467392;   // bf16[20000][256]
constexpr size_t OFF_W1LB     = 33707392;   // bf16[256][256]
constexpr size_t OFF_W1RB     = 33838464;   // bf16[256][256] (end ~34 MB)

static __device__ __forceinline__ unsigned f2bf(float f) {
    unsigned u = __float_as_uint(f);
    return ((u + 0x7fffu + ((u >> 16) & 1u)) >> 16) & 0xffffu;  // RTNE
}

// acc.{lo,hi} += {bf16lo(w), bf16hi(w)} as one v_pk_add_f32 (3 VALU/dword).
static __device__ __forceinline__ void pkacc(f32x2& acc, unsigned w) {
    union { uint2 u; f32x2 f; } t;
    t.u.x = w << 16;
    t.u.y = w & 0xffff0000u;
    asm("v_pk_add_f32 %0, %0, %1" : "+v"(acc) : "v"(t.f));
}

// Fused, 1024-thread blocks (r8: fill2/hist were latency chains at 1 wave/SIMD;
// 1024 threads = 4x fewer serial iters, 4 waves/SIMD).
// Blocks [0,CASTB): cast x/W1l/W1r to bf16 (+ zero s1/t1/bsum);
// blocks [CASTB, CASTB+NB): per-block LDS dst-histogram.
// (r3 lesson: global atomic-with-return CSR build = latency disaster;
// the LDS-histogram rank chain is the fast path.)
__global__ void __launch_bounds__(1024) k_cast_hist(
        const float4* __restrict__ x, const float4* __restrict__ w1l,
        const float4* __restrict__ w1r, uint4* __restrict__ xb,
        uint4* __restrict__ w1lb, uint4* __restrict__ w1rb,
        float* __restrict__ s1, float* __restrict__ t1,
        int* __restrict__ bsum,
        const int* __restrict__ ei, unsigned short* __restrict__ hist) {
    __shared__ unsigned int lh[10000];
    if (blockIdx.x >= CASTB) {   // ---- histogram half ----
        int b = blockIdx.x - CASTB, t = threadIdx.x;
        for (int w = t; w < 10000; w += 1024) lh[w] = 0;
        __syncthreads();
        int base = b * EPB;
        for (int i = t; i < EPB; i += 1024) {
            int d = ei[N_EDGESC + base + i];
            atomicAdd(&lh[d >> 1], (d & 1) ? 0x10000u : 1u);
        }
        __syncthreads();
        unsigned int* gh = (unsigned int*)(hist + (size_t)b * N_NODESC);
        for (int w = t; w < 10000; w += 1024) gh[w] = lh[w];
        return;
    }
    // ---- cast half ----
    int g = blockIdx.x * 1024 + threadIdx.x;   // 8-float group id
    if (g < N_NODESC) { s1[g] = 0.0f; t1[g] = 0.0f; }
    if (g < 128) bsum[g] = 0;
    const float4* src; uint4* dst; int off;
    if (g < 640000)      { src = x;   dst = xb;   off = g; }
    else if (g < 648192) { src = w1l; dst = w1lb; off = g - 640000; }
    else                 { src = w1r; dst = w1rb; off = g - 648192; }
    float4 a = src[off * 2], b = src[off * 2 + 1];
    uint4 o;
    o.x = f2bf(a.x) | (f2bf(a.y) << 16);
    o.y = f2bf(a.z) | (f2bf(a.w) << 16);
    o.z = f2bf(b.x) | (f2bf(b.y) << 16);
    o.w = f2bf(b.z) | (f2bf(b.w) << 16);
    dst[off] = o;
}

// r10: per bin-PAIR exclusive prefix, uint-packed (two 16-bit counters per
// load — same packing as k_hist). Halves block count (157 vs 313) and
// doubles bytes/instr vs the 2-byte-scalar r9 version. Packed arithmetic is
// carry-safe: each half < 2^16 (per-bin degree <= ~200).
__global__ void __launch_bounds__(256) k_prefix(unsigned short* __restrict__ hist,
                                                int* __restrict__ deg,
                                                int* __restrict__ bsum) {
    __shared__ unsigned int wtot[4][64];
    int t = threadIdx.x;
    int lb = t & 63, sub = t >> 6;
    int bp = blockIdx.x * 64 + lb;        // bin pair (bins 2bp, 2bp+1)
    bool ok = bp < 10000;
    unsigned int* hu = (unsigned int*)hist;
    unsigned int vals[64];
    unsigned int run = 0;                 // packed lo/hi running sums
    if (ok) {
        #pragma unroll
        for (int i = 0; i < 64; i++) {
            vals[i] = hu[(size_t)(sub * 64 + i) * 10000 + bp];
            run += vals[i];
        }
    }
    wtot[sub][lb] = run;
    __syncthreads();
    unsigned int off = 0, total = 0;
    for (int w = 0; w < 4; w++) {
        unsigned int v = wtot[w][lb];
        if (w < sub) off += v;
        total += v;
    }
    if (sub == 0) {
        int tv = ok ? (int)((total & 0xffffu) + (total >> 16)) : 0;
        if (ok) {
            deg[2 * bp]     = (int)(total & 0xffffu);
            deg[2 * bp + 1] = (int)(total >> 16);
        }
        #pragma unroll
        for (int o2 = 32; o2 > 0; o2 >>= 1) tv += __shfl_down(tv, o2);
        if (lb == 0) atomicAdd(&bsum[blockIdx.x >> 1], tv);
    }
    if (ok) {
        unsigned int run2 = off;
        #pragma unroll
        for (int i = 0; i < 64; i++) {
            hu[(size_t)(sub * 64 + i) * 10000 + bp] = run2;
            run2 += vals[i];
        }
    }
}

// row_start + inv_deg; absorbs old k_scan2 — each block reduces
// bsum[0..bx) itself (79 ints, L2-hot); row_start[20000] = N_EDGES constant.
__global__ void __launch_bounds__(256) k_scan3(
        const int* __restrict__ deg, const int* __restrict__ bsum,
        int* __restrict__ row_start, float* __restrict__ inv_deg) {
    __shared__ int wsum[4];
    __shared__ int bb[4];
    int i = blockIdx.x * 256 + threadIdx.x;
    int t = threadIdx.x;
    int lane = t & 63, wid = t >> 6;
    // block offset = sum of bsum[w] for w < blockIdx.x  (blockIdx.x <= 78)
    int bv = (t < (int)blockIdx.x) ? bsum[t] : 0;
    #pragma unroll
    for (int off = 32; off > 0; off >>= 1) bv += __shfl_down(bv, off);
    if (lane == 0) bb[wid] = bv;
    int v = (i < N_NODESC) ? deg[i] : 0;
    int incl = v;
    #pragma unroll
    for (int off = 1; off < 64; off <<= 1) {
        int n = __shfl_up(incl, off);
        if (lane >= off) incl += n;
    }
    if (lane == 63) wsum[wid] = incl;
    __syncthreads();
    int boffv = bb[0] + bb[1] + bb[2] + bb[3];
    int wpre = 0;
    #pragma unroll
    for (int w = 0; w < 4; w++) wpre += (w < wid) ? wsum[w] : 0;
    if (i < N_NODESC) {
        row_start[i] = boffv + wpre + incl - v;
        inv_deg[i]   = 1.0f / (float)max(v, 1);
    }
    if (blockIdx.x == 0 && t == 0) row_start[N_NODESC] = N_EDGESC;
}

// scatter edges into CSR (ushort src ids): rank via LDS atomics + hist prefix.
// 1024 threads (5 chain-iters, 4 waves/SIMD); block's hist row staged in LDS.
__global__ void __launch_bounds__(1024) k_fill2(const int* __restrict__ ei,
        const int* __restrict__ row_start, const unsigned short* __restrict__ hist,
        unsigned short* __restrict__ csr) {
    __shared__ unsigned int lh[10000];
    __shared__ unsigned int hbs[10000];
    int b = blockIdx.x, t = threadIdx.x;
    const unsigned int* gh = (const unsigned int*)(hist + (size_t)b * N_NODESC);
    for (int w = t; w < 10000; w += 1024) { lh[w] = 0; hbs[w] = gh[w]; }
    __syncthreads();
    int base = b * EPB;
    for (int i = t; i < EPB; i += 1024) {
        int e = base + i;
        int d = ei[N_EDGESC + e];
        int s = ei[e];
        unsigned int old = atomicAdd(&lh[d >> 1], (d & 1) ? 0x10000u : 1u);
        int rank = (d & 1) ? (int)(old >> 16) : (int)(old & 0xffffu);
        unsigned int hw = hbs[d >> 1];
        int hb = (d & 1) ? (int)(hw >> 16) : (int)(hw & 0xffffu);
        int pos = row_start[d] + hb + rank;
        csr[pos] = (unsigned short)s;
    }
}

// Aggregation, channel-split into 4 passes (blockIdx.y): per-pass gather
// table 2.56 MB < 4 MiB per-XCD L2. 8 lanes x 16B per edge-quarter-row,
// MLP-4 batched gathers, pk_add unpack, window-ahead idx prefetch.
// r9 verdict: dur invariant (53.2) across VALU-count/MLP/occupancy changes —
// formulation at its structural floor (~640K 8-line gather instrs). r10 only
// changes block shape: 1024-thr blocks (16 waves), 4x fewer workgroups.
__global__ void __launch_bounds__(1024) k_agg(const char* __restrict__ xbc,
        const int* __restrict__ row_start, const unsigned short* __restrict__ csr,
        const float* __restrict__ inv_deg, uint4* __restrict__ meanb4) {
    int wid = threadIdx.x >> 6, lane = threadIdx.x & 63;
    int node = blockIdx.x * 16 + wid;
    int pass = blockIdx.y;                 // channel quarter 0..3
    int ol = lane & 7, oct = lane >> 3;
    unsigned lanebyte = ((unsigned)(pass << 3) + (unsigned)ol) << 4;
    int start = row_start[node], end = row_start[node + 1];
    f32x2 pa[4] = {{0,0},{0,0},{0,0},{0,0}};
    f32x2 pc[4] = {{0,0},{0,0},{0,0},{0,0}};
    int idx = (start < end) ? (int)csr[start + lane] : 0;  // <=126B overread ok
    for (int j = start; j < end; j += 64) {
        int cnt = min(64, end - j);
        int idxn = (j + 64 < end) ? (int)csr[j + 64 + lane] : 0;
        int fs = cnt >> 3;                 // full 8-edge steps
        int k = 0;
        for (; k + 4 <= fs; k += 4) {      // 32 edges, 4 loads in flight
            int s0 = __shfl(idx, 8 * k + oct);
            int s1 = __shfl(idx, 8 * k + 8 + oct);
            int s2 = __shfl(idx, 8 * k + 16 + oct);
            int s3 = __shfl(idx, 8 * k + 24 + oct);
            uint4 v0 = *(const uint4*)(xbc + (((unsigned)s0 << 9) + lanebyte));
            uint4 v1 = *(const uint4*)(xbc + (((unsigned)s1 << 9) + lanebyte));
            uint4 v2 = *(const uint4*)(xbc + (((unsigned)s2 << 9) + lanebyte));
            uint4 v3 = *(const uint4*)(xbc + (((unsigned)s3 << 9) + lanebyte));
            pkacc(pa[0], v0.x); pkacc(pa[1], v0.y);
            pkacc(pa[2], v0.z); pkacc(pa[3], v0.w);
            pkacc(pc[0], v1.x); pkacc(pc[1], v1.y);
            pkacc(pc[2], v1.z); pkacc(pc[3], v1.w);
            pkacc(pa[0], v2.x); pkacc(pa[1], v2.y);
            pkacc(pa[2], v2.z); pkacc(pa[3], v2.w);
            pkacc(pc[0], v3.x); pkacc(pc[1], v3.y);
            pkacc(pc[2], v3.z); pkacc(pc[3], v3.w);
        }
        for (; k < fs; k++) {
            int s0 = __shfl(idx, 8 * k + oct);
            uint4 v = *(const uint4*)(xbc + (((unsigned)s0 << 9) + lanebyte));
            pkacc(pa[0], v.x); pkacc(pa[1], v.y);
            pkacc(pa[2], v.z); pkacc(pa[3], v.w);
        }
        int rem = cnt & 7;
        if (rem) {
            int s0 = __shfl(idx, 8 * fs + oct);
            if (oct < rem) {
                uint4 v = *(const uint4*)(xbc + (((unsigned)s0 << 9) + lanebyte));
                pkacc(pc[0], v.x); pkacc(pc[1], v.y);
                pkacc(pc[2], v.z); pkacc(pc[3], v.w);
            }
        }
        idx = idxn;
    }
    pa[0] += pc[0]; pa[1] += pc[1]; pa[2] += pc[2]; pa[3] += pc[3];
    float a0 = pa[0].x, a1 = pa[0].y, a2 = pa[1].x, a3 = pa[1].y;
    float a4 = pa[2].x, a5 = pa[2].y, a6 = pa[3].x, a7 = pa[3].y;
    // cross-octet reduce: lanes ol, ol+8, ..., ol+56 hold the same channels
    a0 += __shfl_down(a0, 32); a1 += __shfl_down(a1, 32);
    a2 += __shfl_down(a2, 32); a3 += __shfl_down(a3, 32);
    a4 += __shfl_down(a4, 32); a5 += __shfl_down(a5, 32);
    a6 += __shfl_down(a6, 32); a7 += __shfl_down(a7, 32);
    a0 += __shfl_down(a0, 16); a1 += __shfl_down(a1, 16);
    a2 += __shfl_down(a2, 16); a3 += __shfl_down(a3, 16);
    a4 += __shfl_down(a4, 16); a5 += __shfl_down(a5, 16);
    a6 += __shfl_down(a6, 16); a7 += __shfl_down(a7, 16);
    a0 += __shfl_down(a0, 8);  a1 += __shfl_down(a1, 8);
    a2 += __shfl_down(a2, 8);  a3 += __shfl_down(a3, 8);
    a4 += __shfl_down(a4, 8);  a5 += __shfl_down(a5, 8);
    a6 += __shfl_down(a6, 8);  a7 += __shfl_down(a7, 8);
    if (oct == 0) {
        float inv = inv_deg[node];
        uint4 o;
        o.x = f2bf(a0 * inv) | (f2bf(a1 * inv) << 16);
        o.y = f2bf(a2 * inv) | (f2bf(a3 * inv) << 16);
        o.z = f2bf(a4 * inv) | (f2bf(a5 * inv) << 16);
        o.w = f2bf(a6 * inv) | (f2bf(a7 * inv) << 16);
        meanb4[(size_t)node * 32 + (pass << 3) + ol] = o;
    }
}

// h1 = relu([mean|x] @ [W1l|W1r]^T + b1) via bf16 MFMA, fused epilogue
// s1 += h1.w2l, t1 += h1.w2r (per-node scalars; h1 never materialized).
// 32 M-rows/block (grid 625), full 256-col weight panel in LDS per K-step.
__global__ void __launch_bounds__(256) k_gemm(const uint4* __restrict__ meanb4,
        const uint4* __restrict__ xb4, const uint4* __restrict__ w1lb4,
        const uint4* __restrict__ w1rb4, const float* __restrict__ b1,
        const float* __restrict__ w2l, const float* __restrict__ w2r,
        float* __restrict__ s1, float* __restrict__ t1) {
    __shared__ __align__(16) unsigned short As[32][72];
    __shared__ __align__(16) unsigned short Bs[256][72];
    int t = threadIdx.x;
    int m0 = blockIdx.x * 32;
    int wv = t >> 6, l = t & 63, lr = l & 15, quad = l >> 4;
    int mh = wv & 1;          // m-half: 16 rows
    int nh = wv >> 1;         // n-half: 8 col-groups of 16
    f32x4 acc[8] = {{0,0,0,0},{0,0,0,0},{0,0,0,0},{0,0,0,0},
                    {0,0,0,0},{0,0,0,0},{0,0,0,0},{0,0,0,0}};
    for (int kt = 0; kt < 8; kt++) {
        const uint4* Asrc = (kt < 4) ? meanb4 : xb4;
        const uint4* Bsrc = (kt < 4) ? w1lb4 : w1rb4;
        int k0q = (kt & 3) * 8;
        {   // A: 32 rows x 8 uint4, 1 load/thread
            int row = t >> 3, cc = t & 7;
            uint4 va = Asrc[(size_t)(m0 + row) * 32 + k0q + cc];
            *(uint4*)&As[row][cc * 8] = va;
        }
        #pragma unroll
        for (int p = 0; p < 8; p++) {   // B: 256 rows x 8 uint4, 8 loads/thread
            int f = p * 256 + t;
            int row = f >> 3, cc = f & 7;
            uint4 vb = Bsrc[(size_t)row * 32 + k0q + cc];
            *(uint4*)&Bs[row][cc * 8] = vb;
        }
        __syncthreads();
        #pragma unroll
        for (int ks = 0; ks < 64; ks += 32) {
            bf16x8 af = *(const bf16x8*)&As[mh * 16 + lr][ks + quad * 8];
            #pragma unroll
            for (int g = 0; g < 8; g++) {
                bf16x8 bf = *(const bf16x8*)&Bs[(nh * 8 + g) * 16 + lr][ks + quad * 8];
                acc[g] = __builtin_amdgcn_mfma_f32_16x16x32_bf16(
                             af, bf, acc[g], 0, 0, 0);
            }
        }
        __syncthreads();
    }
    float ps[4] = {0, 0, 0, 0}, pt[4] = {0, 0, 0, 0};
    #pragma unroll
    for (int g = 0; g < 8; g++) {
        int col = (nh * 8 + g) * 16 + lr;
        float bb = b1[col], wl = w2l[col], wr = w2r[col];
        #pragma unroll
        for (int r = 0; r < 4; r++) {
            float h = fmaxf(acc[g][r] + bb, 0.0f);
            ps[r] += h * wl; pt[r] += h * wr;
        }
    }
    #pragma unroll
    for (int r = 0; r < 4; r++) {
        #pragma unroll
        for (int off = 8; off > 0; off >>= 1) {
            ps[r] += __shfl_down(ps[r], off, 16);
            pt[r] += __shfl_down(pt[r], off, 16);
        }
    }
    if (lr == 0) {
        int mb = m0 + mh * 16 + quad * 4;
        #pragma unroll
        for (int r = 0; r < 4; r++) {
            int m = mb + r;
            atomicAdd(&s1[m], ps[r]);
            atomicAdd(&t1[m], pt[r]);
        }
    }
}

// layer-2 scalar aggregation + epilogue + fc dot; plain-store block partials
__global__ void __launch_bounds__(256) k_layer2(
        const int* __restrict__ row_start, const unsigned short* __restrict__ csr,
        const float* __restrict__ inv_deg, const float* __restrict__ s1,
        const float* __restrict__ t1, const float* __restrict__ b2,
        const float* __restrict__ fc_w, float* __restrict__ part) {
    __shared__ float pw[4];
    int wid = threadIdx.x >> 6, lane = threadIdx.x & 63;
    int node = blockIdx.x * 4 + wid;
    float contrib = 0.0f;
    if (node < N_NODESC) {
        int start = row_start[node], end = row_start[node + 1];
        float s = 0.0f;
        for (int j = start + lane; j < end; j += 64) s += s1[csr[j]];
        #pragma unroll
        for (int off = 32; off > 0; off >>= 1) s += __shfl_down(s, off);
        if (lane == 0) {
            float h2 = fmaxf(s * inv_deg[node] + b2[0] + t1[node], 0.0f);
            contrib = h2 * fc_w[node];
        }
    }
    if (lane == 0) pw[wid] = contrib;
    __syncthreads();
    if (threadIdx.x == 0)
        part[blockIdx.x] = pw[0] + pw[1] + pw[2] + pw[3];
}

// single-block reduction of 5000 partials
__global__ void __launch_bounds__(256) k_final(const float* __restrict__ part,
        const float* __restrict__ fc_b, float* __restrict__ out) {
    __shared__ float sm[4];
    int t = threadIdx.x;
    float s = 0.0f;
    for (int i = t; i < 5000; i += 256) s += part[i];
    #pragma unroll
    for (int off = 32; off > 0; off >>= 1) s += __shfl_down(s, off);
    if ((t & 63) == 0) sm[t >> 6] = s;
    __syncthreads();
    if (t == 0) out[0] = sm[0] + sm[1] + sm[2] + sm[3] + fc_b[0];
}

extern "C" void kernel_launch(void* const* d_in, const int* in_sizes, int n_in,
                              void* d_out, int out_size, void* d_ws, size_t ws_size,
                              hipStream_t stream) {
    const float* x    = (const float*)d_in[0];
    const int*   ei   = (const int*)d_in[1];
    const float* w1l  = (const float*)d_in[2];
    const float* b1   = (const float*)d_in[3];
    const float* w1r  = (const float*)d_in[4];
    const float* w2l  = (const float*)d_in[5];
    const float* b2   = (const float*)d_in[6];
    const float* w2r  = (const float*)d_in[7];
    const float* fcw  = (const float*)d_in[8];
    const float* fcb  = (const float*)d_in[9];
    float* out = (float*)d_out;

    char* ws = (char*)d_ws;
    int*    deg       = (int*)(ws + OFF_DEG);
    int*    row_start = (int*)(ws + OFF_ROWSTART);
    float*  inv_deg   = (float*)(ws + OFF_INVDEG);
    int*    bsum      = (int*)(ws + OFF_BSUM);
    float*  s1        = (float*)(ws + OFF_S1);
    float*  t1        = (float*)(ws + OFF_T1);
    float*  part      = (float*)(ws + OFF_PART);
    unsigned short* hist = (unsigned short*)(ws + OFF_HIST);
    unsigned short* csr  = (unsigned short*)(ws + OFF_CSR);
    char*   xbc       = (char*)(ws + OFF_XB);
    uint4*  meanb4    = (uint4*)(ws + OFF_MEANB);
    uint4*  w1lb4     = (uint4*)(ws + OFF_W1LB);
    uint4*  w1rb4     = (uint4*)(ws + OFF_W1RB);

    k_cast_hist<<<CASTB + NB, 1024, 0, stream>>>(
        (const float4*)x, (const float4*)w1l, (const float4*)w1r,
        (uint4*)xbc, w1lb4, w1rb4, s1, t1, bsum, ei, hist);
    k_prefix<<<157, 256, 0, stream>>>(hist, deg, bsum);
    k_scan3<<<79, 256, 0, stream>>>(deg, bsum, row_start, inv_deg);
    k_fill2<<<NB, 1024, 0, stream>>>(ei, row_start, hist, csr);
    dim3 agrid(1250, 4);
    k_agg<<<agrid, 1024, 0, stream>>>(xbc, row_start, csr, inv_deg, meanb4);
    k_gemm<<<625, 256, 0, stream>>>(meanb4, (const uint4*)xbc,
                                    w1lb4, w1rb4, b1, w2l, w2r, s1, t1);
    k_layer2<<<5000, 256, 0, stream>>>(row_start, csr, inv_deg, s1, t1, b2,
                                       fcw, part);
    k_final<<<1, 256, 0, stream>>>(part, fcb, out);
}

// Round 11
// 201.997 us; speedup vs baseline: 1.0738x; 1.0738x over previous
//
#include <hip/hip_runtime.h>

#define N_NODESC 20000
#define N_EDGESC 1280000
#define NB 256          // csr-build blocks
#define EPB 5000        // edges per build block
#define CASTB 641       // cast blocks (1024 thr) inside fused cast+hist kernel

typedef short bf16x8 __attribute__((ext_vector_type(8)));
typedef float f32x4 __attribute__((ext_vector_type(4)));
typedef float f32x2 __attribute__((ext_vector_type(2)));

// ---- workspace layout (bytes, 16B-aligned) ----
constexpr size_t OFF_DEG      = 0;          // int[20000]
constexpr size_t OFF_ROWSTART = 81920;      // int[20001]
constexpr size_t OFF_INVDEG   = 163840;     // float[20000]
constexpr size_t OFF_BSUM     = 245760;     // int[128]
constexpr size_t OFF_S1       = 246784;     // float[20000]
constexpr size_t OFF_T1       = 326784;     // float[20000]
constexpr size_t OFF_PART     = 406784;     // float[5120] block partials
constexpr size_t OFF_HIST     = 427264;     // ushort[256][20000] = 10.24 MB
constexpr size_t OFF_CSR      = 10667264;   // ushort[1280000] (+128B overread pad)
constexpr size_t OFF_XB       = 13227392;   // bf16[20000][256] row-major = 10.24 MB
constexpr size_t OFF_MEANB    = 23467392;   // bf16[20000][256]
constexpr size_t OFF_W1LB     = 33707392;   // bf16[256][256]
constexpr size_t OFF_W1RB     = 33838464;   // bf16[256][256] (end ~34 MB)

static __device__ __forceinline__ unsigned f2bf(float f) {
    unsigned u = __float_as_uint(f);
    return ((u + 0x7fffu + ((u >> 16) & 1u)) >> 16) & 0xffffu;  // RTNE
}

// acc.{lo,hi} += {bf16lo(w), bf16hi(w)} as one v_pk_add_f32 (3 VALU/dword).
static __device__ __forceinline__ void pkacc(f32x2& acc, unsigned w) {
    union { uint2 u; f32x2 f; } t;
    t.u.x = w << 16;
    t.u.y = w & 0xffff0000u;
    asm("v_pk_add_f32 %0, %0, %1" : "+v"(acc) : "v"(t.f));
}

// Fused, 1024-thread blocks (r8: fill2/hist were latency chains at 1 wave/SIMD;
// 1024 threads = 4x fewer serial iters, 4 waves/SIMD — helps CHAINS, r10
// showed it hurts short variable-length gather waves like k_agg).
// Blocks [0,CASTB): cast x/W1l/W1r to bf16 (+ zero s1/t1/bsum);
// blocks [CASTB, CASTB+NB): per-block LDS dst-histogram.
// (r3 lesson: global atomic-with-return CSR build = latency disaster;
// the LDS-histogram rank chain is the fast path.)
__global__ void __launch_bounds__(1024) k_cast_hist(
        const float4* __restrict__ x, const float4* __restrict__ w1l,
        const float4* __restrict__ w1r, uint4* __restrict__ xb,
        uint4* __restrict__ w1lb, uint4* __restrict__ w1rb,
        float* __restrict__ s1, float* __restrict__ t1,
        int* __restrict__ bsum,
        const int* __restrict__ ei, unsigned short* __restrict__ hist) {
    __shared__ unsigned int lh[10000];
    if (blockIdx.x >= CASTB) {   // ---- histogram half ----
        int b = blockIdx.x - CASTB, t = threadIdx.x;
        for (int w = t; w < 10000; w += 1024) lh[w] = 0;
        __syncthreads();
        int base = b * EPB;
        for (int i = t; i < EPB; i += 1024) {
            int d = ei[N_EDGESC + base + i];
            atomicAdd(&lh[d >> 1], (d & 1) ? 0x10000u : 1u);
        }
        __syncthreads();
        unsigned int* gh = (unsigned int*)(hist + (size_t)b * N_NODESC);
        for (int w = t; w < 10000; w += 1024) gh[w] = lh[w];
        return;
    }
    // ---- cast half ----
    int g = blockIdx.x * 1024 + threadIdx.x;   // 8-float group id
    if (g < N_NODESC) { s1[g] = 0.0f; t1[g] = 0.0f; }
    if (g < 128) bsum[g] = 0;
    const float4* src; uint4* dst; int off;
    if (g < 640000)      { src = x;   dst = xb;   off = g; }
    else if (g < 648192) { src = w1l; dst = w1lb; off = g - 640000; }
    else                 { src = w1r; dst = w1rb; off = g - 648192; }
    float4 a = src[off * 2], b = src[off * 2 + 1];
    uint4 o;
    o.x = f2bf(a.x) | (f2bf(a.y) << 16);
    o.y = f2bf(a.z) | (f2bf(a.w) << 16);
    o.z = f2bf(b.x) | (f2bf(b.y) << 16);
    o.w = f2bf(b.z) | (f2bf(b.w) << 16);
    dst[off] = o;
}

// per bin-PAIR exclusive prefix, uint-packed (two 16-bit counters per load —
// same packing as k_hist). 157 blocks, double bytes/instr vs scalar version.
// Packed arithmetic carry-safe: each half < 2^16.
__global__ void __launch_bounds__(256) k_prefix(unsigned short* __restrict__ hist,
                                                int* __restrict__ deg,
                                                int* __restrict__ bsum) {
    __shared__ unsigned int wtot[4][64];
    int t = threadIdx.x;
    int lb = t & 63, sub = t >> 6;
    int bp = blockIdx.x * 64 + lb;        // bin pair (bins 2bp, 2bp+1)
    bool ok = bp < 10000;
    unsigned int* hu = (unsigned int*)hist;
    unsigned int vals[64];
    unsigned int run = 0;                 // packed lo/hi running sums
    if (ok) {
        #pragma unroll
        for (int i = 0; i < 64; i++) {
            vals[i] = hu[(size_t)(sub * 64 + i) * 10000 + bp];
            run += vals[i];
        }
    }
    wtot[sub][lb] = run;
    __syncthreads();
    unsigned int off = 0, total = 0;
    for (int w = 0; w < 4; w++) {
        unsigned int v = wtot[w][lb];
        if (w < sub) off += v;
        total += v;
    }
    if (sub == 0) {
        int tv = ok ? (int)((total & 0xffffu) + (total >> 16)) : 0;
        if (ok) {
            deg[2 * bp]     = (int)(total & 0xffffu);
            deg[2 * bp + 1] = (int)(total >> 16);
        }
        #pragma unroll
        for (int o2 = 32; o2 > 0; o2 >>= 1) tv += __shfl_down(tv, o2);
        if (lb == 0) atomicAdd(&bsum[blockIdx.x >> 1], tv);
    }
    if (ok) {
        unsigned int run2 = off;
        #pragma unroll
        for (int i = 0; i < 64; i++) {
            hu[(size_t)(sub * 64 + i) * 10000 + bp] = run2;
            run2 += vals[i];
        }
    }
}

// row_start + inv_deg; absorbs old k_scan2 — each block reduces
// bsum[0..bx) itself (79 ints, L2-hot); row_start[20000] = N_EDGES constant.
__global__ void __launch_bounds__(256) k_scan3(
        const int* __restrict__ deg, const int* __restrict__ bsum,
        int* __restrict__ row_start, float* __restrict__ inv_deg) {
    __shared__ int wsum[4];
    __shared__ int bb[4];
    int i = blockIdx.x * 256 + threadIdx.x;
    int t = threadIdx.x;
    int lane = t & 63, wid = t >> 6;
    // block offset = sum of bsum[w] for w < blockIdx.x  (blockIdx.x <= 78)
    int bv = (t < (int)blockIdx.x) ? bsum[t] : 0;
    #pragma unroll
    for (int off = 32; off > 0; off >>= 1) bv += __shfl_down(bv, off);
    if (lane == 0) bb[wid] = bv;
    int v = (i < N_NODESC) ? deg[i] : 0;
    int incl = v;
    #pragma unroll
    for (int off = 1; off < 64; off <<= 1) {
        int n = __shfl_up(incl, off);
        if (lane >= off) incl += n;
    }
    if (lane == 63) wsum[wid] = incl;
    __syncthreads();
    int boffv = bb[0] + bb[1] + bb[2] + bb[3];
    int wpre = 0;
    #pragma unroll
    for (int w = 0; w < 4; w++) wpre += (w < wid) ? wsum[w] : 0;
    if (i < N_NODESC) {
        row_start[i] = boffv + wpre + incl - v;
        inv_deg[i]   = 1.0f / (float)max(v, 1);
    }
    if (blockIdx.x == 0 && t == 0) row_start[N_NODESC] = N_EDGESC;
}

// scatter edges into CSR (ushort src ids): rank via LDS atomics + hist prefix.
// 1024 threads (5 chain-iters, 4 waves/SIMD); block's hist row staged in LDS.
__global__ void __launch_bounds__(1024) k_fill2(const int* __restrict__ ei,
        const int* __restrict__ row_start, const unsigned short* __restrict__ hist,
        unsigned short* __restrict__ csr) {
    __shared__ unsigned int lh[10000];
    __shared__ unsigned int hbs[10000];
    int b = blockIdx.x, t = threadIdx.x;
    const unsigned int* gh = (const unsigned int*)(hist + (size_t)b * N_NODESC);
    for (int w = t; w < 10000; w += 1024) { lh[w] = 0; hbs[w] = gh[w]; }
    __syncthreads();
    int base = b * EPB;
    for (int i = t; i < EPB; i += 1024) {
        int e = base + i;
        int d = ei[N_EDGESC + e];
        int s = ei[e];
        unsigned int old = atomicAdd(&lh[d >> 1], (d & 1) ? 0x10000u : 1u);
        int rank = (d & 1) ? (int)(old >> 16) : (int)(old & 0xffffu);
        unsigned int hw = hbs[d >> 1];
        int hb = (d & 1) ? (int)(hw >> 16) : (int)(hw & 0xffffu);
        int pos = row_start[d] + hb + rank;
        csr[pos] = (unsigned short)s;
    }
}

// Aggregation, channel-split into 4 passes (blockIdx.y): per-pass gather
// table 2.56 MB < 4 MiB per-XCD L2. 8 lanes x 16B per edge-quarter-row,
// MLP-4 batched gathers, pk_add unpack, window-ahead idx prefetch.
// 256-thr / 4-wave blocks (r10: 1024-thr blocks = -23% via block-granule
// occupancy + variable-degree tail; reverted). dur invariant at ~53.2us
// across VALU-count/MLP/occupancy/packing changes (r5/r6/r9/r10) —
// formulation at its structural floor; do not touch the inner loop.
__global__ void __launch_bounds__(256) k_agg(const char* __restrict__ xbc,
        const int* __restrict__ row_start, const unsigned short* __restrict__ csr,
        const float* __restrict__ inv_deg, uint4* __restrict__ meanb4) {
    int wid = threadIdx.x >> 6, lane = threadIdx.x & 63;
    int node = blockIdx.x * 4 + wid;
    int pass = blockIdx.y;                 // channel quarter 0..3
    int ol = lane & 7, oct = lane >> 3;
    unsigned lanebyte = ((unsigned)(pass << 3) + (unsigned)ol) << 4;
    int start = row_start[node], end = row_start[node + 1];
    f32x2 pa[4] = {{0,0},{0,0},{0,0},{0,0}};
    f32x2 pc[4] = {{0,0},{0,0},{0,0},{0,0}};
    int idx = (start < end) ? (int)csr[start + lane] : 0;  // <=126B overread ok
    for (int j = start; j < end; j += 64) {
        int cnt = min(64, end - j);
        int idxn = (j + 64 < end) ? (int)csr[j + 64 + lane] : 0;
        int fs = cnt >> 3;                 // full 8-edge steps
        int k = 0;
        for (; k + 4 <= fs; k += 4) {      // 32 edges, 4 loads in flight
            int s0 = __shfl(idx, 8 * k + oct);
            int s1 = __shfl(idx, 8 * k + 8 + oct);
            int s2 = __shfl(idx, 8 * k + 16 + oct);
            int s3 = __shfl(idx, 8 * k + 24 + oct);
            uint4 v0 = *(const uint4*)(xbc + (((unsigned)s0 << 9) + lanebyte));
            uint4 v1 = *(const uint4*)(xbc + (((unsigned)s1 << 9) + lanebyte));
            uint4 v2 = *(const uint4*)(xbc + (((unsigned)s2 << 9) + lanebyte));
            uint4 v3 = *(const uint4*)(xbc + (((unsigned)s3 << 9) + lanebyte));
            pkacc(pa[0], v0.x); pkacc(pa[1], v0.y);
            pkacc(pa[2], v0.z); pkacc(pa[3], v0.w);
            pkacc(pc[0], v1.x); pkacc(pc[1], v1.y);
            pkacc(pc[2], v1.z); pkacc(pc[3], v1.w);
            pkacc(pa[0], v2.x); pkacc(pa[1], v2.y);
            pkacc(pa[2], v2.z); pkacc(pa[3], v2.w);
            pkacc(pc[0], v3.x); pkacc(pc[1], v3.y);
            pkacc(pc[2], v3.z); pkacc(pc[3], v3.w);
        }
        for (; k < fs; k++) {
            int s0 = __shfl(idx, 8 * k + oct);
            uint4 v = *(const uint4*)(xbc + (((unsigned)s0 << 9) + lanebyte));
            pkacc(pa[0], v.x); pkacc(pa[1], v.y);
            pkacc(pa[2], v.z); pkacc(pa[3], v.w);
        }
        int rem = cnt & 7;
        if (rem) {
            int s0 = __shfl(idx, 8 * fs + oct);
            if (oct < rem) {
                uint4 v = *(const uint4*)(xbc + (((unsigned)s0 << 9) + lanebyte));
                pkacc(pc[0], v.x); pkacc(pc[1], v.y);
                pkacc(pc[2], v.z); pkacc(pc[3], v.w);
            }
        }
        idx = idxn;
    }
    pa[0] += pc[0]; pa[1] += pc[1]; pa[2] += pc[2]; pa[3] += pc[3];
    float a0 = pa[0].x, a1 = pa[0].y, a2 = pa[1].x, a3 = pa[1].y;
    float a4 = pa[2].x, a5 = pa[2].y, a6 = pa[3].x, a7 = pa[3].y;
    // cross-octet reduce: lanes ol, ol+8, ..., ol+56 hold the same channels
    a0 += __shfl_down(a0, 32); a1 += __shfl_down(a1, 32);
    a2 += __shfl_down(a2, 32); a3 += __shfl_down(a3, 32);
    a4 += __shfl_down(a4, 32); a5 += __shfl_down(a5, 32);
    a6 += __shfl_down(a6, 32); a7 += __shfl_down(a7, 32);
    a0 += __shfl_down(a0, 16); a1 += __shfl_down(a1, 16);
    a2 += __shfl_down(a2, 16); a3 += __shfl_down(a3, 16);
    a4 += __shfl_down(a4, 16); a5 += __shfl_down(a5, 16);
    a6 += __shfl_down(a6, 16); a7 += __shfl_down(a7, 16);
    a0 += __shfl_down(a0, 8);  a1 += __shfl_down(a1, 8);
    a2 += __shfl_down(a2, 8);  a3 += __shfl_down(a3, 8);
    a4 += __shfl_down(a4, 8);  a5 += __shfl_down(a5, 8);
    a6 += __shfl_down(a6, 8);  a7 += __shfl_down(a7, 8);
    if (oct == 0) {
        float inv = inv_deg[node];
        uint4 o;
        o.x = f2bf(a0 * inv) | (f2bf(a1 * inv) << 16);
        o.y = f2bf(a2 * inv) | (f2bf(a3 * inv) << 16);
        o.z = f2bf(a4 * inv) | (f2bf(a5 * inv) << 16);
        o.w = f2bf(a6 * inv) | (f2bf(a7 * inv) << 16);
        meanb4[(size_t)node * 32 + (pass << 3) + ol] = o;
    }
}

// h1 = relu([mean|x] @ [W1l|W1r]^T + b1) via bf16 MFMA, fused epilogue
// s1 += h1.w2l, t1 += h1.w2r (per-node scalars; h1 never materialized).
// 32 M-rows/block (grid 625), full 256-col weight panel in LDS per K-step.
__global__ void __launch_bounds__(256) k_gemm(const uint4* __restrict__ meanb4,
        const uint4* __restrict__ xb4, const uint4* __restrict__ w1lb4,
        const uint4* __restrict__ w1rb4, const float* __restrict__ b1,
        const float* __restrict__ w2l, const float* __restrict__ w2r,
        float* __restrict__ s1, float* __restrict__ t1) {
    __shared__ __align__(16) unsigned short As[32][72];
    __shared__ __align__(16) unsigned short Bs[256][72];
    int t = threadIdx.x;
    int m0 = blockIdx.x * 32;
    int wv = t >> 6, l = t & 63, lr = l & 15, quad = l >> 4;
    int mh = wv & 1;          // m-half: 16 rows
    int nh = wv >> 1;         // n-half: 8 col-groups of 16
    f32x4 acc[8] = {{0,0,0,0},{0,0,0,0},{0,0,0,0},{0,0,0,0},
                    {0,0,0,0},{0,0,0,0},{0,0,0,0},{0,0,0,0}};
    for (int kt = 0; kt < 8; kt++) {
        const uint4* Asrc = (kt < 4) ? meanb4 : xb4;
        const uint4* Bsrc = (kt < 4) ? w1lb4 : w1rb4;
        int k0q = (kt & 3) * 8;
        {   // A: 32 rows x 8 uint4, 1 load/thread
            int row = t >> 3, cc = t & 7;
            uint4 va = Asrc[(size_t)(m0 + row) * 32 + k0q + cc];
            *(uint4*)&As[row][cc * 8] = va;
        }
        #pragma unroll
        for (int p = 0; p < 8; p++) {   // B: 256 rows x 8 uint4, 8 loads/thread
            int f = p * 256 + t;
            int row = f >> 3, cc = f & 7;
            uint4 vb = Bsrc[(size_t)row * 32 + k0q + cc];
            *(uint4*)&Bs[row][cc * 8] = vb;
        }
        __syncthreads();
        #pragma unroll
        for (int ks = 0; ks < 64; ks += 32) {
            bf16x8 af = *(const bf16x8*)&As[mh * 16 + lr][ks + quad * 8];
            #pragma unroll
            for (int g = 0; g < 8; g++) {
                bf16x8 bf = *(const bf16x8*)&Bs[(nh * 8 + g) * 16 + lr][ks + quad * 8];
                acc[g] = __builtin_amdgcn_mfma_f32_16x16x32_bf16(
                             af, bf, acc[g], 0, 0, 0);
            }
        }
        __syncthreads();
    }
    float ps[4] = {0, 0, 0, 0}, pt[4] = {0, 0, 0, 0};
    #pragma unroll
    for (int g = 0; g < 8; g++) {
        int col = (nh * 8 + g) * 16 + lr;
        float bb = b1[col], wl = w2l[col], wr = w2r[col];
        #pragma unroll
        for (int r = 0; r < 4; r++) {
            float h = fmaxf(acc[g][r] + bb, 0.0f);
            ps[r] += h * wl; pt[r] += h * wr;
        }
    }
    #pragma unroll
    for (int r = 0; r < 4; r++) {
        #pragma unroll
        for (int off = 8; off > 0; off >>= 1) {
            ps[r] += __shfl_down(ps[r], off, 16);
            pt[r] += __shfl_down(pt[r], off, 16);
        }
    }
    if (lr == 0) {
        int mb = m0 + mh * 16 + quad * 4;
        #pragma unroll
        for (int r = 0; r < 4; r++) {
            int m = mb + r;
            atomicAdd(&s1[m], ps[r]);
            atomicAdd(&t1[m], pt[r]);
        }
    }
}

// layer-2 scalar aggregation + epilogue + fc dot; plain-store block partials
__global__ void __launch_bounds__(256) k_layer2(
        const int* __restrict__ row_start, const unsigned short* __restrict__ csr,
        const float* __restrict__ inv_deg, const float* __restrict__ s1,
        const float* __restrict__ t1, const float* __restrict__ b2,
        const float* __restrict__ fc_w, float* __restrict__ part) {
    __shared__ float pw[4];
    int wid = threadIdx.x >> 6, lane = threadIdx.x & 63;
    int node = blockIdx.x * 4 + wid;
    float contrib = 0.0f;
    if (node < N_NODESC) {
        int start = row_start[node], end = row_start[node + 1];
        float s = 0.0f;
        for (int j = start + lane; j < end; j += 64) s += s1[csr[j]];
        #pragma unroll
        for (int off = 32; off > 0; off >>= 1) s += __shfl_down(s, off);
        if (lane == 0) {
            float h2 = fmaxf(s * inv_deg[node] + b2[0] + t1[node], 0.0f);
            contrib = h2 * fc_w[node];
        }
    }
    if (lane == 0) pw[wid] = contrib;
    __syncthreads();
    if (threadIdx.x == 0)
        part[blockIdx.x] = pw[0] + pw[1] + pw[2] + pw[3];
}

// single-block reduction of 5000 partials
__global__ void __launch_bounds__(256) k_final(const float* __restrict__ part,
        const float* __restrict__ fc_b, float* __restrict__ out) {
    __shared__ float sm[4];
    int t = threadIdx.x;
    float s = 0.0f;
    for (int i = t; i < 5000; i += 256) s += part[i];
    #pragma unroll
    for (int off = 32; off > 0; off >>= 1) s += __shfl_down(s, off);
    if ((t & 63) == 0) sm[t >> 6] = s;
    __syncthreads();
    if (t == 0) out[0] = sm[0] + sm[1] + sm[2] + sm[3] + fc_b[0];
}

extern "C" void kernel_launch(void* const* d_in, const int* in_sizes, int n_in,
                              void* d_out, int out_size, void* d_ws, size_t ws_size,
                              hipStream_t stream) {
    const float* x    = (const float*)d_in[0];
    const int*   ei   = (const int*)d_in[1];
    const float* w1l  = (const float*)d_in[2];
    const float* b1   = (const float*)d_in[3];
    const float* w1r  = (const float*)d_in[4];
    const float* w2l  = (const float*)d_in[5];
    const float* b2   = (const float*)d_in[6];
    const float* w2r  = (const float*)d_in[7];
    const float* fcw  = (const float*)d_in[8];
    const float* fcb  = (const float*)d_in[9];
    float* out = (float*)d_out;

    char* ws = (char*)d_ws;
    int*    deg       = (int*)(ws + OFF_DEG);
    int*    row_start = (int*)(ws + OFF_ROWSTART);
    float*  inv_deg   = (float*)(ws + OFF_INVDEG);
    int*    bsum      = (int*)(ws + OFF_BSUM);
    float*  s1        = (float*)(ws + OFF_S1);
    float*  t1        = (float*)(ws + OFF_T1);
    float*  part      = (float*)(ws + OFF_PART);
    unsigned short* hist = (unsigned short*)(ws + OFF_HIST);
    unsigned short* csr  = (unsigned short*)(ws + OFF_CSR);
    char*   xbc       = (char*)(ws + OFF_XB);
    uint4*  meanb4    = (uint4*)(ws + OFF_MEANB);
    uint4*  w1lb4     = (uint4*)(ws + OFF_W1LB);
    uint4*  w1rb4     = (uint4*)(ws + OFF_W1RB);

    k_cast_hist<<<CASTB + NB, 1024, 0, stream>>>(
        (const float4*)x, (const float4*)w1l, (const float4*)w1r,
        (uint4*)xbc, w1lb4, w1rb4, s1, t1, bsum, ei, hist);
    k_prefix<<<157, 256, 0, stream>>>(hist, deg, bsum);
    k_scan3<<<79, 256, 0, stream>>>(deg, bsum, row_start, inv_deg);
    k_fill2<<<NB, 1024, 0, stream>>>(ei, row_start, hist, csr);
    dim3 agrid(5000, 4);
    k_agg<<<agrid, 256, 0, stream>>>(xbc, row_start, csr, inv_deg, meanb4);
    k_gemm<<<625, 256, 0, stream>>>(meanb4, (const uint4*)xbc,
                                    w1lb4, w1rb4, b1, w2l, w2r, s1, t1);
    k_layer2<<<5000, 256, 0, stream>>>(row_start, csr, inv_deg, s1, t1, b2,
                                       fcw, part);
    k_final<<<1, 256, 0, stream>>>(part, fcb, out);
}